// Round 13
// baseline (4372.506 us; speedup 1.0000x reference)
//
#include <hip/hip_runtime.h>
#include <hip/hip_bf16.h>
#include <cstdio>

typedef __hip_bfloat16 bf16;
typedef __attribute__((ext_vector_type(8))) short short8v;
typedef __attribute__((ext_vector_type(4))) float f32x4;

#define T_WIN 1993      // N_WINDOWS
#define NSER 512
#define NTIME 2048
#define NGRP 32
#define FLAGS_INTS (4*8*NGRP)

// s_waitcnt immediates (gfx9 encoding)
#define WAIT_LGKM0 0xC07F   // lgkmcnt(0) only
#define WAIT_VM0   0x0F70   // vmcnt(0) only

// shared-memory layout (carved from one kernel-scope block):
//   [0, 2304)              hbuf: 2 × 16×72
//   [2304, 2304+8*16*72)   xring: 2 bufs × 4 steps × 16×XSTR (XSTR ≤ 72)
#define SMEM_USHORTS (2304 + 8*16*72)   // 11520 ushorts = 23040 B

__device__ __forceinline__ float sigmf(float x) { return __fdividef(1.f, 1.f + __expf(-x)); }
__device__ __forceinline__ float tanhf_fast(float x) { return 1.f - __fdividef(2.f, __expf(2.f*x) + 1.f); }
__device__ __forceinline__ ushort f2bfu(float f) {
  __hip_bfloat16 h = __float2bfloat16(f);
  return *reinterpret_cast<ushort*>(&h);
}

// ---------------- ES scan: 1 thread per series ----------------
__global__ void es_kernel(const float* __restrict__ y, const int* __restrict__ idxs,
                          const float* __restrict__ lev_sms, const float* __restrict__ seas_sms,
                          const float* __restrict__ init_seas,
                          float* __restrict__ levels, float* __restrict__ seas) {
  int s = blockIdx.x*blockDim.x + threadIdx.x;
  if (s >= NSER) return;
  int id = idxs[s];
  float ls = sigmf(lev_sms[id]);
  float ss = sigmf(seas_sms[id]);
  float buf[8];
  #pragma unroll
  for (int k=0;k<7;++k) buf[k] = __expf(init_seas[id*7+k]);
  buf[7] = buf[0];
  const float* yr = y + (size_t)s*NTIME;
  float* lr = levels + (size_t)s*NTIME;
  float* sr = seas + (size_t)s*NTIME;
  float lev = __fdividef(yr[0], buf[0]);
  lr[0] = lev;
  #pragma unroll
  for (int t=0;t<8;++t) sr[t] = buf[t];
  #pragma unroll 8
  for (int t=1;t<NTIME;++t) {
    float yt = yr[t];
    float st = buf[1];
    lev = ls*__fdividef(yt,st) + (1.f-ls)*lev;
    float ns = ss*__fdividef(yt,lev) + (1.f-ss)*st;
    #pragma unroll
    for (int k=0;k<7;++k) buf[k] = buf[k+1];
    buf[7] = ns;
    lr[t] = lev;
    if (t+7 < NTIME) sr[t+7] = ns;
  }
}

// ---------------- log(norm), log(levels) ----------------
__global__ void lnorm_kernel(const float* __restrict__ y, const float* __restrict__ seas,
                             const float* __restrict__ levels,
                             float* __restrict__ lnorm, float* __restrict__ llev) {
  int i = blockIdx.x*256 + threadIdx.x;
  lnorm[i] = __logf(__fdividef(y[i], seas[i]));
  llev[i]  = __logf(levels[i]);
}

// ---------------- windows: windows_y (out0) + RNN input xhat ----------------
__global__ void window_kernel(const float* __restrict__ lnorm, const float* __restrict__ llev,
                              const float* __restrict__ noise,
                              float* __restrict__ wy, ushort* __restrict__ xhat) {
  int idx = blockIdx.x*256 + threadIdx.x;   // (w*512 + s)*28 + k
  int k  = idx % 28;
  int rs = idx / 28;
  int s  = rs & 511;
  int w  = rs >> 9;
  float lv = llev[s*NTIME + 28 + w];
  const float* Ln = lnorm + s*NTIME;
  wy[idx]   = Ln[w+28+k] - lv;
  xhat[idx] = f2bfu(Ln[w+k] - lv + 0.001f*noise[idx]);
}

// ---------------- fused 4-layer pipelined LSTM scan (production) -----------
// r13 = r12 with the LDS blowup fixed: ONE kernel-scope shared block shared
// by all template instantiations (r12: four function-scope __shared__ sets
// summed to 82 KB -> 1 block/CU -> broken pipeline overlap).
// Steady-state steps contain ZERO register-dest VMEM: x staged
// global->regs->LDS-ring at 4-step chunk boundaries, h burst-stored per chunk.
template<int KXS, int LAYER>
__device__ __forceinline__ void lstm_scan(
    ushort* __restrict__ sm,
    const ushort* __restrict__ xin, ushort* __restrict__ hout,
    const float* __restrict__ Wih, const float* __restrict__ Whh,
    const float* __restrict__ bih, const float* __restrict__ bhh,
    const int j, const int g, int* __restrict__ flags)
{
  constexpr int KST  = KXS + 2;
  constexpr int D    = (KXS == 1) ? 28 : 64;
  constexpr int KX   = KXS * 32;
  constexpr int RATE = 1 << LAYER;
  constexpr int SRCR = (LAYER > 0) ? (RATE >> 1) : 1;
  constexpr int XSTR = (KXS == 1) ? 40 : 72;   // x row stride (units)

  ushort* hb  = sm;           // hbuf: [2][16*72]
  ushort* xr0 = sm + 2304;    // xring: [2][4][16*XSTR]

  const int i    = threadIdx.x;
  const int lane = i & 63;
  const int wid  = i >> 6;
  const int n15  = lane & 15;
  const int kq   = lane >> 4;
  const int base = g * 16;
  const int wm   = i >> 4;
  const int wu   = (i & 15) * 4;
  const int sr14 = i / 14, sc14 = i - sr14*14;   // D==28 staging coords (i<224)

  short8v wfrag[4][KST];
  float bias[4];
  #pragma unroll
  for (int gg = 0; gg < 4; ++gg) {
    const int R = gg*64 + wid*16 + n15;
    bias[gg] = bih[R] + bhh[R];
    #pragma unroll
    for (int kk = 0; kk < KST; ++kk) {
      #pragma unroll
      for (int jj = 0; jj < 8; ++jj) {
        const int k = kk*32 + kq*8 + jj;
        float v;
        if (k < KX) v = (k < D) ? Wih[R*D + k] : 0.f;
        else        v = Whh[R*64 + (k - KX)];
        wfrag[gg][kk][jj] = (short)f2bfu(v);
      }
    }
  }

  for (int e = i; e < 1152; e += 256) hb[e] = 0;
  for (int e = i; e < 8*16*XSTR; e += 256) xr0[e] = 0;   // incl. K-pad
  __syncthreads();

  const int nsteps = (T_WIN - 1 - j)/RATE + 1;
  const int u = wid*16 + n15;
  float cc[4] = {0.f, 0.f, 0.f, 0.f};

  int* myflag = &flags[(LAYER*8 + j)*NGRP + g];
  int* fp = nullptr;
  int seen0 = 0;
  int prodmax = 0x7fffffff;
  if constexpr (LAYER > 0) {
    const int pp0 = j % SRCR;
    fp = &flags[((LAYER-1)*8 + pp0)*NGRP + g];
    prodmax = (T_WIN - 1 - pp0)/SRCR + 1;
  }

  auto wait_for = [&](int t) __attribute__((always_inline)) {
    if constexpr (LAYER > 0) {
      const int tc = (t < T_WIN) ? t : (T_WIN - 1);
      int need = tc/SRCR + 1;
      need = (need < prodmax) ? need : prodmax;
      if (seen0 >= need) return;
      while (__hip_atomic_load(fp, __ATOMIC_RELAXED, __HIP_MEMORY_SCOPE_AGENT) < need)
        __builtin_amdgcn_s_sleep(8);
      seen0 = __hip_atomic_load(fp, __ATOMIC_ACQUIRE, __HIP_MEMORY_SCOPE_AGENT);
    }
  };

  // -------- chunk staging (4 t's per chunk) --------
  uint  g28[4];
  uint2 g64[4];

  auto loadG = [&](int chunk) __attribute__((always_inline)) {
    #pragma unroll
    for (int q = 0; q < 4; ++q) {
      int t = j + (chunk*4 + q)*RATE;
      const int tc = (t < T_WIN) ? t : (T_WIN - 1);
      if constexpr (KXS == 1) {
        if (i < 224)
          g28[q] = *reinterpret_cast<const uint*>(xin + ((size_t)tc*512 + base + sr14)*28 + sc14*2);
      } else {
        g64[q] = *reinterpret_cast<const uint2*>(xin + ((size_t)tc*512 + base + (i>>4))*64 + (i&15)*4);
      }
    }
  };
  auto writeG = [&](int buf) __attribute__((always_inline)) {
    #pragma unroll
    for (int q = 0; q < 4; ++q) {
      ushort* dst = xr0 + (buf*4 + q)*16*XSTR;
      if constexpr (KXS == 1) {
        if (i < 224)
          *reinterpret_cast<uint*>(&dst[sr14*40 + sc14*2]) = g28[q];
      } else {
        *reinterpret_cast<uint2*>(&dst[(i>>4)*72 + (i&15)*4]) = g64[q];
      }
    }
  };

  // -------- one recurrence step: LDS-only --------
  auto stepc = [&](int S, uint2* hv) __attribute__((always_inline)) {
    const int p_ = S & 1;
    const ushort* xr = xr0 + (((S>>2)&1)*4 + (S&3))*16*XSTR;
    short8v xa = *reinterpret_cast<const short8v*>(xr + n15*XSTR + kq*8);
    short8v xb;
    if constexpr (KXS == 2) xb = *reinterpret_cast<const short8v*>(xr + n15*XSTR + 32 + kq*8);
    const ushort* hbp = hb + p_*1152;
    short8v hf0 = *reinterpret_cast<const short8v*>(hbp + n15*72 + kq*8);
    short8v hf1 = *reinterpret_cast<const short8v*>(hbp + n15*72 + 32 + kq*8);
    *hv = *reinterpret_cast<const uint2*>(hbp + wm*72 + wu);
    f32x4 acc0 = {bias[0], bias[0], bias[0], bias[0]};
    f32x4 acc1 = {bias[1], bias[1], bias[1], bias[1]};
    f32x4 acc2 = {bias[2], bias[2], bias[2], bias[2]};
    f32x4 acc3 = {bias[3], bias[3], bias[3], bias[3]};
    acc0 = __builtin_amdgcn_mfma_f32_16x16x32_bf16(xa, wfrag[0][0], acc0, 0, 0, 0);
    acc1 = __builtin_amdgcn_mfma_f32_16x16x32_bf16(xa, wfrag[1][0], acc1, 0, 0, 0);
    acc2 = __builtin_amdgcn_mfma_f32_16x16x32_bf16(xa, wfrag[2][0], acc2, 0, 0, 0);
    acc3 = __builtin_amdgcn_mfma_f32_16x16x32_bf16(xa, wfrag[3][0], acc3, 0, 0, 0);
    if constexpr (KXS == 2) {
      acc0 = __builtin_amdgcn_mfma_f32_16x16x32_bf16(xb, wfrag[0][1], acc0, 0, 0, 0);
      acc1 = __builtin_amdgcn_mfma_f32_16x16x32_bf16(xb, wfrag[1][1], acc1, 0, 0, 0);
      acc2 = __builtin_amdgcn_mfma_f32_16x16x32_bf16(xb, wfrag[2][1], acc2, 0, 0, 0);
      acc3 = __builtin_amdgcn_mfma_f32_16x16x32_bf16(xb, wfrag[3][1], acc3, 0, 0, 0);
    }
    acc0 = __builtin_amdgcn_mfma_f32_16x16x32_bf16(hf0, wfrag[0][KXS], acc0, 0, 0, 0);
    acc1 = __builtin_amdgcn_mfma_f32_16x16x32_bf16(hf0, wfrag[1][KXS], acc1, 0, 0, 0);
    acc2 = __builtin_amdgcn_mfma_f32_16x16x32_bf16(hf0, wfrag[2][KXS], acc2, 0, 0, 0);
    acc3 = __builtin_amdgcn_mfma_f32_16x16x32_bf16(hf0, wfrag[3][KXS], acc3, 0, 0, 0);
    acc0 = __builtin_amdgcn_mfma_f32_16x16x32_bf16(hf1, wfrag[0][KXS+1], acc0, 0, 0, 0);
    acc1 = __builtin_amdgcn_mfma_f32_16x16x32_bf16(hf1, wfrag[1][KXS+1], acc1, 0, 0, 0);
    acc2 = __builtin_amdgcn_mfma_f32_16x16x32_bf16(hf1, wfrag[2][KXS+1], acc2, 0, 0, 0);
    acc3 = __builtin_amdgcn_mfma_f32_16x16x32_bf16(hf1, wfrag[3][KXS+1], acc3, 0, 0, 0);
    ushort* hbn = hb + (p_^1)*1152;
    #pragma unroll
    for (int r = 0; r < 4; ++r) {
      const float zi = acc0[r], zf = acc1[r], zg = acc2[r], zo = acc3[r];
      cc[r] = sigmf(zf)*cc[r] + sigmf(zi)*tanhf_fast(zg);
      const float h_ = sigmf(zo)*tanhf_fast(cc[r]);
      hbn[(kq*4 + r)*72 + u] = f2bfu(h_);
    }
    __builtin_amdgcn_sched_barrier(0);
    __builtin_amdgcn_s_waitcnt(WAIT_LGKM0);   // own ds ops only
    __builtin_amdgcn_sched_barrier(0);
    __builtin_amdgcn_s_barrier();             // raw barrier: no vmcnt drain
  };

  auto sth = [&](int t, uint2 hv) __attribute__((always_inline)) {
    *reinterpret_cast<uint2*>(&hout[((size_t)t*512 + base + wm)*64 + wu]) = hv;
  };

  // -------- prologue: stage chunks 0,1 synchronously; chunk 2 in flight ----
  wait_for(j + 11*RATE);
  loadG(0); __builtin_amdgcn_s_waitcnt(WAIT_VM0); writeG(0);
  loadG(1); __builtin_amdgcn_s_waitcnt(WAIT_VM0); writeG(1);
  loadG(2);                                   // stays pending (counted)
  __builtin_amdgcn_s_waitcnt(WAIT_LGKM0);
  __builtin_amdgcn_s_barrier();

  uint2 hh0, hh1, hh2, hh3;
  stepc(0, &hh0);
  stepc(1, &hh1);
  stepc(2, &hh2);
  stepc(3, &hh3);
  sth(j,          hh1);
  sth(j +   RATE, hh2);
  sth(j + 2*RATE, hh3);

  int B = 4;
  for (; B + 4 <= nsteps; B += 4) {
    const int c = B >> 2;
    wait_for(j + (B + 11)*RATE);
    writeG((c + 1) & 1);     // chunk c+1 (G loaded at previous boundary)
    loadG(c + 2);            // consumed by writeG at next boundary
    stepc(B+0, &hh0);
    stepc(B+1, &hh1);
    stepc(B+2, &hh2);
    stepc(B+3, &hh3);
    sth(j + (B-1)*RATE, hh0);
    sth(j + (B  )*RATE, hh1);
    sth(j + (B+1)*RATE, hh2);
    sth(j + (B+2)*RATE, hh3);
    if constexpr (LAYER < 3) {
      __builtin_amdgcn_s_waitcnt(WAIT_VM0);
      __builtin_amdgcn_s_barrier();
      if (i == 0)
        __hip_atomic_store(myflag, B+3, __ATOMIC_RELEASE, __HIP_MEMORY_SCOPE_AGENT);
    }
  }
  for (; B < nsteps; ++B) {    // tail (<4 steps): x already staged
    uint2 hvT;
    stepc(B, &hvT);
    sth(j + (B-1)*RATE, hvT);
  }

  {
    const int pF = nsteps & 1;
    const int tF = j + (nsteps - 1)*RATE;
    uint2 hv = *reinterpret_cast<const uint2*>(hb + pF*1152 + wm*72 + wu);
    sth(tF, hv);
  }
  if constexpr (LAYER < 3) {
    __builtin_amdgcn_s_waitcnt(WAIT_VM0);
    __builtin_amdgcn_s_barrier();
    if (i == 0)
      __hip_atomic_store(myflag, nsteps, __ATOMIC_RELEASE, __HIP_MEMORY_SCOPE_AGENT);
  }
}

__global__ __launch_bounds__(256, 2)
void lstm_fused(const ushort* __restrict__ xhat,
                ushort* __restrict__ h1, ushort* __restrict__ h2, ushort* __restrict__ h4,
                const float* __restrict__ Wih0, const float* __restrict__ Wih_rest,
                const float* __restrict__ Whh_all,
                const float* __restrict__ bih_all, const float* __restrict__ bhh_all,
                int* __restrict__ flags)
{
  __shared__ __align__(16) ushort smem[SMEM_USHORTS];   // ONE block, all paths
  const int bid = blockIdx.x;
  ushort* h3 = h1;   // alias safe: h1[t]'s only reader (L2) consumes it before
                     // h2[t] is published, which gates L3's write.
  if (bid < 32) {
    lstm_scan<1,0>(smem, xhat, h1, Wih0, Whh_all, bih_all, bhh_all,
                   0, bid, flags);
  } else if (bid < 96) {
    lstm_scan<2,1>(smem, h1, h2, Wih_rest, Whh_all + 256*64, bih_all + 256, bhh_all + 256,
                   (bid-32) >> 5, (bid-32) & 31, flags);
  } else if (bid < 224) {
    lstm_scan<2,2>(smem, h2, h3, Wih_rest + 256*64, Whh_all + 2*256*64, bih_all + 2*256, bhh_all + 2*256,
                   (bid-96) >> 5, (bid-96) & 31, flags);
  } else {
    lstm_scan<2,3>(smem, h3, h4, Wih_rest + 2*256*64, Whh_all + 3*256*64, bih_all + 3*256, bhh_all + 3*256,
                   (bid-224) >> 5, (bid-224) & 31, flags);
  }
}

// ---------------- adapter: out1 = (h4+h2) @ adW.T + adb ----------------
__global__ __launch_bounds__(256) void adapter_kernel(const ushort* __restrict__ h4, const ushort* __restrict__ h2,
      const float* __restrict__ adW, const float* __restrict__ adb, float* __restrict__ out) {
  __shared__ __align__(16) float xrow[64*64];
  const int i = threadIdx.x;
  const int total = T_WIN*512;
  const int base = blockIdx.x * 64;
  for (int e = i; e < 64*64; e += 256) {
    int r = e >> 6;
    size_t gi = (size_t)(base + r)*64 + (e & 63);
    float v = 0.f;
    if (base + r < total) {
      __hip_bfloat16 a = *reinterpret_cast<const __hip_bfloat16*>(h4 + gi);
      __hip_bfloat16 b = *reinterpret_cast<const __hip_bfloat16*>(h2 + gi);
      v = __bfloat162float(a) + __bfloat162float(b);
    }
    xrow[e] = v;
  }
  const int o  = i & 31;
  const int rg = i >> 5;
  float w[64]; float bo = 0.f;
  if (o < 28) {
    #pragma unroll
    for (int uu=0;uu<64;++uu) w[uu] = adW[o*64+uu];
    bo = adb[o];
  }
  __syncthreads();
  if (o < 28) {
    #pragma unroll
    for (int rr=0; rr<8; ++rr) {
      int r = rg*8 + rr;
      if (base + r >= total) break;
      const float4* xp = (const float4*)(&xrow[r*64]);
      float a0 = bo, a1 = 0.f, a2 = 0.f, a3 = 0.f;
      #pragma unroll
      for (int q=0;q<16;++q) {
        float4 xv = xp[q];
        a0 += w[4*q+0]*xv.x; a1 += w[4*q+1]*xv.y;
        a2 += w[4*q+2]*xv.z; a3 += w[4*q+3]*xv.w;
      }
      out[(size_t)(base+r)*28 + o] = (a0+a1)+(a2+a3);
    }
  }
}

extern "C" void kernel_launch(void* const* d_in, const int* in_sizes, int n_in,
                              void* d_out, int out_size, void* d_ws, size_t ws_size,
                              hipStream_t stream) {
  const float* y         = (const float*)d_in[0];
  const int*   idxs      = (const int*)d_in[1];
  const float* noise     = (const float*)d_in[2];
  const float* lev_sms   = (const float*)d_in[3];
  const float* seas_sms  = (const float*)d_in[4];
  const float* init_seas = (const float*)d_in[5];
  const float* Wih0      = (const float*)d_in[6];
  const float* Wih_rest  = (const float*)d_in[7];
  const float* Whh_all   = (const float*)d_in[8];
  const float* bih_all   = (const float*)d_in[9];
  const float* bhh_all   = (const float*)d_in[10];
  const float* adW       = (const float*)d_in[11];
  const float* adb       = (const float*)d_in[12];

  const size_t NWIN28 = (size_t)T_WIN*512*28;
  const size_t NWIN64 = (size_t)T_WIN*512*64;
  float* out_wy   = (float*)d_out;
  float* out_yhat = out_wy + NWIN28;
  float* out_lev  = out_yhat + NWIN28;

  int*   flags = (int*)d_ws;                       // 4 KiB reserved
  float* seas  = (float*)((char*)d_ws + 4096);
  float* lnorm = seas  + (size_t)NSER*NTIME;
  float* llev  = lnorm + (size_t)NSER*NTIME;
  ushort* xhat = (ushort*)(llev + (size_t)NSER*NTIME);
  ushort* h1   = (ushort*)((char*)xhat + NWIN28*2);
  ushort* h2   = (ushort*)((char*)h1 + NWIN64*2);
  ushort* h4   = (ushort*)((char*)h2 + NWIN64*2);

  size_t need = 4096 + (size_t)3*NSER*NTIME*4 + NWIN28*2 + 3*NWIN64*2;
  if (ws_size < need) {
    fprintf(stderr, "kernel_launch: ws_size %zu < needed %zu\n", ws_size, need);
    return;
  }

  hipMemsetAsync(flags, 0, FLAGS_INTS*sizeof(int), stream);
  es_kernel<<<2,256,0,stream>>>(y, idxs, lev_sms, seas_sms, init_seas, out_lev, seas);
  lnorm_kernel<<<(NSER*NTIME)/256,256,0,stream>>>(y, seas, out_lev, lnorm, llev);
  window_kernel<<<NWIN28/256,256,0,stream>>>(lnorm, llev, noise, out_wy, xhat);

  lstm_fused<<<480,256,0,stream>>>(xhat, h1, h2, h4, Wih0, Wih_rest, Whh_all,
                                   bih_all, bhh_all, flags);

  adapter_kernel<<<(T_WIN*512)/64,256,0,stream>>>(h4, h2, adW, adb, out_yhat);
}

// Round 14
// 3627.206 us; speedup vs baseline: 1.2055x; 1.2055x over previous
//
#include <hip/hip_runtime.h>
#include <hip/hip_bf16.h>
#include <cstdio>

typedef __hip_bfloat16 bf16;
typedef __attribute__((ext_vector_type(8))) short short8v;
typedef __attribute__((ext_vector_type(4))) float f32x4;

#define T_WIN 1993      // N_WINDOWS
#define NSER 512
#define NTIME 2048
#define NGRP 32
#define FLAGS_INTS (4*8*NGRP)

#define WAIT_LGKM0 0xC07F   // lgkmcnt(0) only
#define WAIT_VM0   0x0F70   // vmcnt(0) only

#define SMEM_USHORTS 2304   // hbuf: 2 × 16×72 ushorts (4608 B)

__device__ __forceinline__ float sigmf(float x) { return __fdividef(1.f, 1.f + __expf(-x)); }
__device__ __forceinline__ float tanhf_fast(float x) { return 1.f - __fdividef(2.f, __expf(2.f*x) + 1.f); }
__device__ __forceinline__ ushort f2bfu(float f) {
  __hip_bfloat16 h = __float2bfloat16(f);
  return *reinterpret_cast<ushort*>(&h);
}
__device__ __forceinline__ float bfu2f(ushort u) {
  uint x = ((uint)u) << 16;
  return __uint_as_float(x);
}

// ---------------- ES scan: 1 thread per series ----------------
__global__ void es_kernel(const float* __restrict__ y, const int* __restrict__ idxs,
                          const float* __restrict__ lev_sms, const float* __restrict__ seas_sms,
                          const float* __restrict__ init_seas,
                          float* __restrict__ levels, float* __restrict__ seas) {
  int s = blockIdx.x*blockDim.x + threadIdx.x;
  if (s >= NSER) return;
  int id = idxs[s];
  float ls = sigmf(lev_sms[id]);
  float ss = sigmf(seas_sms[id]);
  float buf[8];
  #pragma unroll
  for (int k=0;k<7;++k) buf[k] = __expf(init_seas[id*7+k]);
  buf[7] = buf[0];
  const float* yr = y + (size_t)s*NTIME;
  float* lr = levels + (size_t)s*NTIME;
  float* sr = seas + (size_t)s*NTIME;
  float lev = __fdividef(yr[0], buf[0]);
  lr[0] = lev;
  #pragma unroll
  for (int t=0;t<8;++t) sr[t] = buf[t];
  #pragma unroll 8
  for (int t=1;t<NTIME;++t) {
    float yt = yr[t];
    float st = buf[1];
    lev = ls*__fdividef(yt,st) + (1.f-ls)*lev;
    float ns = ss*__fdividef(yt,lev) + (1.f-ss)*st;
    #pragma unroll
    for (int k=0;k<7;++k) buf[k] = buf[k+1];
    buf[7] = ns;
    lr[t] = lev;
    if (t+7 < NTIME) sr[t+7] = ns;
  }
}

// ---------------- log(norm), log(levels) ----------------
__global__ void lnorm_kernel(const float* __restrict__ y, const float* __restrict__ seas,
                             const float* __restrict__ levels,
                             float* __restrict__ lnorm, float* __restrict__ llev) {
  int i = blockIdx.x*256 + threadIdx.x;
  lnorm[i] = __logf(__fdividef(y[i], seas[i]));
  llev[i]  = __logf(levels[i]);
}

// ---------------- windows: windows_y (out0) + RNN input xhat ----------------
__global__ void window_kernel(const float* __restrict__ lnorm, const float* __restrict__ llev,
                              const float* __restrict__ noise,
                              float* __restrict__ wy, ushort* __restrict__ xhat) {
  int idx = blockIdx.x*256 + threadIdx.x;   // (w*512 + s)*28 + k
  int k  = idx % 28;
  int rs = idx / 28;
  int s  = rs & 511;
  int w  = rs >> 9;
  float lv = llev[s*NTIME + 28 + w];
  const float* Ln = lnorm + s*NTIME;
  wy[idx]   = Ln[w+28+k] - lv;
  xhat[idx] = f2bfu(Ln[w+k] - lv + 0.001f*noise[idx]);
}

// ---------------- fused 4-layer pipelined LSTM scan (production) -----------
// r14 = r9 base (4-deep register x rotation, per-chunk burst h stores) with
// the per-step MFMA DEPENDENCY CHAIN shortened from 3-4 levels to 1:
//  - xacc[g] = bias + x_t @ Wx computed ONE STEP EARLY (off the h-chain);
//  - h contribution split into parallel accumulators A (hf0, C=xacc) and
//    B (hf1, C=0), merged with a VALU add at gate time.
template<int KXS, int LAYER>
__device__ __forceinline__ void lstm_scan(
    ushort* __restrict__ hb,
    const ushort* __restrict__ xin, ushort* __restrict__ hout,
    const float* __restrict__ Wih, const float* __restrict__ Whh,
    const float* __restrict__ bih, const float* __restrict__ bhh,
    const int j, const int g, int* __restrict__ flags)
{
  constexpr int KST  = KXS + 2;
  constexpr int D    = (KXS == 1) ? 28 : 64;
  constexpr int KX   = KXS * 32;
  constexpr int RATE = 1 << LAYER;
  constexpr int SRCR = (LAYER > 0) ? (RATE >> 1) : 1;

  const int i    = threadIdx.x;
  const int lane = i & 63;
  const int wid  = i >> 6;
  const int n15  = lane & 15;
  const int kq   = lane >> 4;
  const int base = g * 16;
  const int wm   = i >> 4;
  const int wu   = (i & 15) * 4;
  const uint km  = (kq == 3) ? 0u : ~0u;

  short8v wfrag[4][KST];
  float bias[4];
  #pragma unroll
  for (int gg = 0; gg < 4; ++gg) {
    const int R = gg*64 + wid*16 + n15;
    bias[gg] = bih[R] + bhh[R];
    #pragma unroll
    for (int kk = 0; kk < KST; ++kk) {
      #pragma unroll
      for (int jj = 0; jj < 8; ++jj) {
        const int k = kk*32 + kq*8 + jj;
        float v;
        if (k < KX) v = (k < D) ? Wih[R*D + k] : 0.f;
        else        v = Whh[R*64 + (k - KX)];
        wfrag[gg][kk][jj] = (short)f2bfu(v);
      }
    }
  }
  f32x4 biasv[4];
  #pragma unroll
  for (int gg = 0; gg < 4; ++gg)
    biasv[gg] = (f32x4){bias[gg], bias[gg], bias[gg], bias[gg]};
  const f32x4 zv = (f32x4){0.f, 0.f, 0.f, 0.f};

  for (int e = i; e < 1152; e += 256) hb[e] = 0;
  __syncthreads();

  const int nsteps = (T_WIN - 1 - j)/RATE + 1;
  const int u = wid*16 + n15;
  float cc[4] = {0.f, 0.f, 0.f, 0.f};

  int* myflag = &flags[(LAYER*8 + j)*NGRP + g];
  int* fp = nullptr;
  int seen0 = 0;
  int prodmax = 0x7fffffff;
  if constexpr (LAYER > 0) {
    const int pp0 = j % SRCR;
    fp = &flags[((LAYER-1)*8 + pp0)*NGRP + g];
    prodmax = (T_WIN - 1 - pp0)/SRCR + 1;
  }

  auto wait_for = [&](int t) __attribute__((always_inline)) {
    if constexpr (LAYER > 0) {
      const int tc = (t < T_WIN) ? t : (T_WIN - 1);
      int need = tc/SRCR + 1;
      need = (need < prodmax) ? need : prodmax;
      if (seen0 >= need) return;
      while (__hip_atomic_load(fp, __ATOMIC_RELAXED, __HIP_MEMORY_SCOPE_AGENT) < need)
        __builtin_amdgcn_s_sleep(8);
      seen0 = __hip_atomic_load(fp, __ATOMIC_ACQUIRE, __HIP_MEMORY_SCOPE_AGENT);
    }
  };

  auto loadx = [&](int t, short8v* xf) __attribute__((always_inline)) {
    const int tc = (t < T_WIN) ? t : (T_WIN - 1);
    const ushort* p = xin + ((size_t)tc*512 + base + n15)*(size_t)D + kq*8;
    if constexpr (D == 64) {
      xf[0] = *reinterpret_cast<const short8v*>(p);
      xf[1] = *reinterpret_cast<const short8v*>(p + 32);
    } else {
      ushort4 a = *reinterpret_cast<const ushort4*>(p);
      ushort4 b = *reinterpret_cast<const ushort4*>(p + 4);
      short8v r;
      r[0]=(short)a.x; r[1]=(short)a.y; r[2]=(short)a.z; r[3]=(short)a.w;
      r[4]=(short)(ushort)(b.x & km); r[5]=(short)(ushort)(b.y & km);
      r[6]=(short)(ushort)(b.z & km); r[7]=(short)(ushort)(b.w & km);
      xf[0] = r;
    }
  };

  // xacc for time t from fragment set xf (off the h-chain)
  auto xmm = [&](const short8v* xf, f32x4* xa) __attribute__((always_inline)) {
    #pragma unroll
    for (int gg = 0; gg < 4; ++gg) {
      f32x4 t = __builtin_amdgcn_mfma_f32_16x16x32_bf16(xf[0], wfrag[gg][0], biasv[gg], 0, 0, 0);
      if constexpr (KXS == 2)
        t = __builtin_amdgcn_mfma_f32_16x16x32_bf16(xf[1], wfrag[gg][1], t, 0, 0, 0);
      xa[gg] = t;
    }
  };

  // one step: consume xaC (= bias + x_S@Wx); h-chain is ONE MFMA level.
  // If doNext: also compute xaN for step S+1 from xfN and reload xfN<-x(tN).
  auto stepc = [&](int S, const f32x4* xaC, f32x4* xaN, short8v* xfN, int tN,
                   uint2* hv, bool doNext) __attribute__((always_inline)) {
    const int p_ = S & 1;
    const ushort* hbp = hb + p_*1152;
    short8v hf0 = *reinterpret_cast<const short8v*>(hbp + n15*72 + kq*8);
    short8v hf1 = *reinterpret_cast<const short8v*>(hbp + n15*72 + 32 + kq*8);
    *hv = *reinterpret_cast<const uint2*>(hbp + wm*72 + wu);
    f32x4 A0 = __builtin_amdgcn_mfma_f32_16x16x32_bf16(hf0, wfrag[0][KXS], xaC[0], 0, 0, 0);
    f32x4 A1 = __builtin_amdgcn_mfma_f32_16x16x32_bf16(hf0, wfrag[1][KXS], xaC[1], 0, 0, 0);
    f32x4 A2 = __builtin_amdgcn_mfma_f32_16x16x32_bf16(hf0, wfrag[2][KXS], xaC[2], 0, 0, 0);
    f32x4 A3 = __builtin_amdgcn_mfma_f32_16x16x32_bf16(hf0, wfrag[3][KXS], xaC[3], 0, 0, 0);
    f32x4 B0 = __builtin_amdgcn_mfma_f32_16x16x32_bf16(hf1, wfrag[0][KXS+1], zv, 0, 0, 0);
    f32x4 B1 = __builtin_amdgcn_mfma_f32_16x16x32_bf16(hf1, wfrag[1][KXS+1], zv, 0, 0, 0);
    f32x4 B2 = __builtin_amdgcn_mfma_f32_16x16x32_bf16(hf1, wfrag[2][KXS+1], zv, 0, 0, 0);
    f32x4 B3 = __builtin_amdgcn_mfma_f32_16x16x32_bf16(hf1, wfrag[3][KXS+1], zv, 0, 0, 0);
    if (doNext) {
      xmm(xfN, xaN);        // next step's x-part (off-chain)
      loadx(tN, xfN);       // reload the just-consumed set (4-step slack)
    }
    ushort* hbn = hb + (p_^1)*1152;
    #pragma unroll
    for (int r = 0; r < 4; ++r) {
      const float zi = A0[r] + B0[r];
      const float zf = A1[r] + B1[r];
      const float zg = A2[r] + B2[r];
      const float zo = A3[r] + B3[r];
      cc[r] = sigmf(zf)*cc[r] + sigmf(zi)*tanhf_fast(zg);
      const float h_ = sigmf(zo)*tanhf_fast(cc[r]);
      hbn[(kq*4 + r)*72 + u] = f2bfu(h_);
    }
    __builtin_amdgcn_sched_barrier(0);
    __builtin_amdgcn_s_waitcnt(WAIT_LGKM0);
    __builtin_amdgcn_sched_barrier(0);
    __builtin_amdgcn_s_barrier();
  };

  auto sth = [&](int t, uint2 hv) __attribute__((always_inline)) {
    *reinterpret_cast<uint2*>(&hout[((size_t)t*512 + base + wm)*64 + wu]) = hv;
  };

  short8v xf0[KXS], xf1[KXS], xf2[KXS], xf3[KXS];
  f32x4 xaP[4], xaQ[4];
  uint2 hh0, hh1, hh2, hh3;

  // prologue: sets 0..3 <- x0..x3; xacc(0); set0 reloaded with x4
  wait_for(j + 8*RATE);
  loadx(j, xf0);
  xmm(xf0, xaP);            // xacc for step 0 (waits set0's load; prologue only)
  loadx(j + 4*RATE, xf0);   // set0 <- x4
  loadx(j +   RATE, xf1);
  loadx(j + 2*RATE, xf2);
  loadx(j + 3*RATE, xf3);

  // chunk 0 peeled (no store of h_{-1})
  stepc(0, xaP, xaQ, xf1, j + 5*RATE, &hh0, true);
  stepc(1, xaQ, xaP, xf2, j + 6*RATE, &hh1, true);
  stepc(2, xaP, xaQ, xf3, j + 7*RATE, &hh2, true);
  stepc(3, xaQ, xaP, xf0, j + 8*RATE, &hh3, true);
  sth(j,          hh1);
  sth(j +   RATE, hh2);
  sth(j + 2*RATE, hh3);

  int B = 4;
  for (; B + 4 <= nsteps; B += 4) {
    wait_for(j + (B + 8)*RATE);   // covers loads x(B+5)..x(B+8)
    stepc(B+0, xaP, xaQ, xf1, j + (B+5)*RATE, &hh0, true);
    stepc(B+1, xaQ, xaP, xf2, j + (B+6)*RATE, &hh1, true);
    stepc(B+2, xaP, xaQ, xf3, j + (B+7)*RATE, &hh2, true);
    stepc(B+3, xaQ, xaP, xf0, j + (B+8)*RATE, &hh3, true);
    sth(j + (B-1)*RATE, hh0);
    sth(j + (B  )*RATE, hh1);
    sth(j + (B+1)*RATE, hh2);
    sth(j + (B+2)*RATE, hh3);
    if constexpr (LAYER < 3) {
      if ((B & 7) == 4) {
        __builtin_amdgcn_s_waitcnt(WAIT_VM0);
        __builtin_amdgcn_s_barrier();
        if (i == 0)
          __hip_atomic_store(myflag, B+3, __ATOMIC_RELEASE, __HIP_MEMORY_SCOPE_AGENT);
      }
    }
  }
  for (; B < nsteps; ++B) {       // tail (<4 steps): consume only
    uint2 hvT;
    if (B & 1) stepc(B, xaQ, nullptr, nullptr, 0, &hvT, false);
    else       stepc(B, xaP, nullptr, nullptr, 0, &hvT, false);
    sth(j + (B-1)*RATE, hvT);
  }

  {
    const int pF = nsteps & 1;
    const int tF = j + (nsteps - 1)*RATE;
    uint2 hv = *reinterpret_cast<const uint2*>(hb + pF*1152 + wm*72 + wu);
    sth(tF, hv);
  }
  if constexpr (LAYER < 3) {
    __builtin_amdgcn_s_waitcnt(WAIT_VM0);
    __builtin_amdgcn_s_barrier();
    if (i == 0)
      __hip_atomic_store(myflag, nsteps, __ATOMIC_RELEASE, __HIP_MEMORY_SCOPE_AGENT);
  }
}

__global__ __launch_bounds__(256, 2)
void lstm_fused(const ushort* __restrict__ xhat,
                ushort* __restrict__ h1, ushort* __restrict__ h2, ushort* __restrict__ h4,
                const float* __restrict__ Wih0, const float* __restrict__ Wih_rest,
                const float* __restrict__ Whh_all,
                const float* __restrict__ bih_all, const float* __restrict__ bhh_all,
                int* __restrict__ flags)
{
  __shared__ __align__(16) ushort smem[SMEM_USHORTS];   // one block, all paths
  const int bid = blockIdx.x;
  ushort* h3 = h1;   // alias safe: h1[t]'s only reader (L2) consumes it before
                     // h2[t] is published, which gates L3's write.
  if (bid < 32) {
    lstm_scan<1,0>(smem, xhat, h1, Wih0, Whh_all, bih_all, bhh_all,
                   0, bid, flags);
  } else if (bid < 96) {
    lstm_scan<2,1>(smem, h1, h2, Wih_rest, Whh_all + 256*64, bih_all + 256, bhh_all + 256,
                   (bid-32) >> 5, (bid-32) & 31, flags);
  } else if (bid < 224) {
    lstm_scan<2,2>(smem, h2, h3, Wih_rest + 256*64, Whh_all + 2*256*64, bih_all + 2*256, bhh_all + 2*256,
                   (bid-96) >> 5, (bid-96) & 31, flags);
  } else {
    lstm_scan<2,3>(smem, h3, h4, Wih_rest + 2*256*64, Whh_all + 3*256*64, bih_all + 3*256, bhh_all + 3*256,
                   (bid-224) >> 5, (bid-224) & 31, flags);
  }
}

// ---------------- adapter: out1 = (h4+h2) @ adW.T + adb ----------------
__global__ __launch_bounds__(256) void adapter_kernel(const ushort* __restrict__ h4, const ushort* __restrict__ h2,
      const float* __restrict__ adW, const float* __restrict__ adb, float* __restrict__ out) {
  __shared__ __align__(16) float xrow[64*64];
  const int i = threadIdx.x;
  const int total = T_WIN*512;
  const int base = blockIdx.x * 64;
  // vectorized bf16 loads: 8 bf16 (16 B) per iteration per thread (G13)
  for (int e = i; e < 512; e += 256) {
    const int r  = e >> 3;
    const int c8 = (e & 7) * 8;
    size_t gi = (size_t)(base + r)*64 + c8;
    if (base + r < total) {
      uint4 a = *reinterpret_cast<const uint4*>(h4 + gi);
      uint4 b = *reinterpret_cast<const uint4*>(h2 + gi);
      const uint* au = &a.x; const uint* bu = &b.x;
      #pragma unroll
      for (int q = 0; q < 4; ++q) {
        uint av = au[q], bv = bu[q];
        xrow[r*64 + c8 + 2*q]     = bfu2f((ushort)(av & 0xFFFF)) + bfu2f((ushort)(bv & 0xFFFF));
        xrow[r*64 + c8 + 2*q + 1] = bfu2f((ushort)(av >> 16))    + bfu2f((ushort)(bv >> 16));
      }
    } else {
      #pragma unroll
      for (int q = 0; q < 8; ++q) xrow[r*64 + c8 + q] = 0.f;
    }
  }
  const int o  = i & 31;
  const int rg = i >> 5;
  float w[64]; float bo = 0.f;
  if (o < 28) {
    #pragma unroll
    for (int uu=0;uu<64;++uu) w[uu] = adW[o*64+uu];
    bo = adb[o];
  }
  __syncthreads();
  if (o < 28) {
    #pragma unroll
    for (int rr=0; rr<8; ++rr) {
      int r = rg*8 + rr;
      if (base + r >= total) break;
      const float4* xp = (const float4*)(&xrow[r*64]);
      float a0 = bo, a1 = 0.f, a2 = 0.f, a3 = 0.f;
      #pragma unroll
      for (int q=0;q<16;++q) {
        float4 xv = xp[q];
        a0 += w[4*q+0]*xv.x; a1 += w[4*q+1]*xv.y;
        a2 += w[4*q+2]*xv.z; a3 += w[4*q+3]*xv.w;
      }
      out[(size_t)(base+r)*28 + o] = (a0+a1)+(a2+a3);
    }
  }
}

extern "C" void kernel_launch(void* const* d_in, const int* in_sizes, int n_in,
                              void* d_out, int out_size, void* d_ws, size_t ws_size,
                              hipStream_t stream) {
  const float* y         = (const float*)d_in[0];
  const int*   idxs      = (const int*)d_in[1];
  const float* noise     = (const float*)d_in[2];
  const float* lev_sms   = (const float*)d_in[3];
  const float* seas_sms  = (const float*)d_in[4];
  const float* init_seas = (const float*)d_in[5];
  const float* Wih0      = (const float*)d_in[6];
  const float* Wih_rest  = (const float*)d_in[7];
  const float* Whh_all   = (const float*)d_in[8];
  const float* bih_all   = (const float*)d_in[9];
  const float* bhh_all   = (const float*)d_in[10];
  const float* adW       = (const float*)d_in[11];
  const float* adb       = (const float*)d_in[12];

  const size_t NWIN28 = (size_t)T_WIN*512*28;
  const size_t NWIN64 = (size_t)T_WIN*512*64;
  float* out_wy   = (float*)d_out;
  float* out_yhat = out_wy + NWIN28;
  float* out_lev  = out_yhat + NWIN28;

  int*   flags = (int*)d_ws;                       // 4 KiB reserved
  float* seas  = (float*)((char*)d_ws + 4096);
  float* lnorm = seas  + (size_t)NSER*NTIME;
  float* llev  = lnorm + (size_t)NSER*NTIME;
  ushort* xhat = (ushort*)(llev + (size_t)NSER*NTIME);
  ushort* h1   = (ushort*)((char*)xhat + NWIN28*2);
  ushort* h2   = (ushort*)((char*)h1 + NWIN64*2);
  ushort* h4   = (ushort*)((char*)h2 + NWIN64*2);

  size_t need = 4096 + (size_t)3*NSER*NTIME*4 + NWIN28*2 + 3*NWIN64*2;
  if (ws_size < need) {
    fprintf(stderr, "kernel_launch: ws_size %zu < needed %zu\n", ws_size, need);
    return;
  }

  hipMemsetAsync(flags, 0, FLAGS_INTS*sizeof(int), stream);
  es_kernel<<<2,256,0,stream>>>(y, idxs, lev_sms, seas_sms, init_seas, out_lev, seas);
  lnorm_kernel<<<(NSER*NTIME)/256,256,0,stream>>>(y, seas, out_lev, lnorm, llev);
  window_kernel<<<NWIN28/256,256,0,stream>>>(lnorm, llev, noise, out_wy, xhat);

  lstm_fused<<<480,256,0,stream>>>(xhat, h1, h2, h4, Wih0, Wih_rest, Whh_all,
                                   bih_all, bhh_all, flags);

  adapter_kernel<<<(T_WIN*512)/64,256,0,stream>>>(h4, h2, adW, adb, out_yhat);
}

// Round 15
// 3295.156 us; speedup vs baseline: 1.3269x; 1.1008x over previous
//
#include <hip/hip_runtime.h>
#include <hip/hip_bf16.h>
#include <cstdio>

typedef __hip_bfloat16 bf16;
typedef __attribute__((ext_vector_type(8))) short short8v;
typedef __attribute__((ext_vector_type(4))) float f32x4;

#define T_WIN 1993      // N_WINDOWS
#define NSER 512
#define NTIME 2048
#define NGRP 32
#define FLAGS_INTS (4*8*NGRP)

#define WAIT_LGKM0 0xC07F   // lgkmcnt(0) only
#define WAIT_VM0   0x0F70   // vmcnt(0) only

#define SMEM_USHORTS 2304   // hbuf: 2 × 16×72 ushorts (4608 B)

__device__ __forceinline__ float sigmf(float x) { return __fdividef(1.f, 1.f + __expf(-x)); }
__device__ __forceinline__ float tanhf_fast(float x) { return 1.f - __fdividef(2.f, __expf(2.f*x) + 1.f); }
__device__ __forceinline__ ushort f2bfu(float f) {
  __hip_bfloat16 h = __float2bfloat16(f);
  return *reinterpret_cast<ushort*>(&h);
}
__device__ __forceinline__ float bfu2f(ushort u) {
  uint x = ((uint)u) << 16;
  return __uint_as_float(x);
}

// ---------------- y[s][t] -> yT[t][s] (LDS-tiled, conflict-free) -----------
__global__ __launch_bounds__(256) void transpose_y(const float* __restrict__ y,
                                                   float* __restrict__ yT) {
  __shared__ float tile[64][65];
  const int i  = threadIdx.x;
  const int c  = i & 63;
  const int r4 = i >> 6;
  const int t0 = (blockIdx.x & 31) * 64;
  const int s0 = (blockIdx.x >> 5) * 64;
  #pragma unroll
  for (int q = 0; q < 16; ++q) {
    const int sl = q*4 + r4;
    tile[c][sl] = y[(size_t)(s0 + sl)*NTIME + t0 + c];   // read: lanes vary t ✓
  }
  __syncthreads();
  #pragma unroll
  for (int q = 0; q < 16; ++q) {
    const int tl = q*4 + r4;
    yT[(size_t)(t0 + tl)*NSER + s0 + c] = tile[tl][c];   // write: lanes vary s ✓
  }
}

// ---------------- ES scan (transposed layouts; all accesses coalesced) -----
__global__ void es_kernel_t(const float* __restrict__ yT, const int* __restrict__ idxs,
                            const float* __restrict__ lev_sms, const float* __restrict__ seas_sms,
                            const float* __restrict__ init_seas,
                            float* __restrict__ levT, float* __restrict__ seasT) {
  int s = blockIdx.x*blockDim.x + threadIdx.x;
  if (s >= NSER) return;
  int id = idxs[s];
  float ls = sigmf(lev_sms[id]);
  float ss = sigmf(seas_sms[id]);
  float buf[8];
  #pragma unroll
  for (int k=0;k<7;++k) buf[k] = __expf(init_seas[id*7+k]);
  buf[7] = buf[0];
  float lev = __fdividef(yT[s], buf[0]);
  levT[s] = lev;
  #pragma unroll
  for (int t=0;t<8;++t) seasT[t*NSER + s] = buf[t];
  #pragma unroll 8
  for (int t=1;t<NTIME;++t) {
    float yt = yT[t*NSER + s];
    float st = buf[1];
    lev = ls*__fdividef(yt,st) + (1.f-ls)*lev;
    float ns = ss*__fdividef(yt,lev) + (1.f-ss)*st;
    #pragma unroll
    for (int k=0;k<7;++k) buf[k] = buf[k+1];
    buf[7] = ns;
    levT[t*NSER + s] = lev;
    if (t+7 < NTIME) seasT[(t+7)*NSER + s] = ns;
  }
}

// ------- transpose back + fused logs: out_lev/lnorm/llev in [s][t] ---------
__global__ __launch_bounds__(256) void trlog_kernel(const float* __restrict__ y,
        const float* __restrict__ levT, const float* __restrict__ seasT,
        float* __restrict__ out_lev, float* __restrict__ lnorm, float* __restrict__ llev) {
  __shared__ float tl[64][65];
  __shared__ float ts[64][65];
  const int i  = threadIdx.x;
  const int c  = i & 63;
  const int r4 = i >> 6;
  const int t0 = (blockIdx.x & 31) * 64;
  const int s0 = (blockIdx.x >> 5) * 64;
  #pragma unroll
  for (int q = 0; q < 16; ++q) {
    const int tl_ = q*4 + r4;
    const size_t src = (size_t)(t0 + tl_)*NSER + s0 + c;   // lanes vary s ✓
    tl[tl_][c] = levT[src];
    ts[tl_][c] = seasT[src];
  }
  __syncthreads();
  #pragma unroll
  for (int q = 0; q < 16; ++q) {
    const int sl = q*4 + r4;
    const size_t o = (size_t)(s0 + sl)*NTIME + t0 + c;     // lanes vary t ✓
    const float lv = tl[c][sl];
    const float sv = ts[c][sl];
    out_lev[o] = lv;
    llev[o]    = __logf(lv);
    lnorm[o]   = __logf(__fdividef(y[o], sv));
  }
}

// ---------------- windows: windows_y (out0) + RNN input xhat ----------------
__global__ void window_kernel(const float* __restrict__ lnorm, const float* __restrict__ llev,
                              const float* __restrict__ noise,
                              float* __restrict__ wy, ushort* __restrict__ xhat) {
  int idx = blockIdx.x*256 + threadIdx.x;   // (w*512 + s)*28 + k
  int k  = idx % 28;
  int rs = idx / 28;
  int s  = rs & 511;
  int w  = rs >> 9;
  float lv = llev[s*NTIME + 28 + w];
  const float* Ln = lnorm + s*NTIME;
  wy[idx]   = Ln[w+28+k] - lv;
  xhat[idx] = f2bfu(Ln[w+k] - lv + 0.001f*noise[idx]);
}

// ---------------- fused 4-layer pipelined LSTM scan (production, r14) ------
template<int KXS, int LAYER>
__device__ __forceinline__ void lstm_scan(
    ushort* __restrict__ hb,
    const ushort* __restrict__ xin, ushort* __restrict__ hout,
    const float* __restrict__ Wih, const float* __restrict__ Whh,
    const float* __restrict__ bih, const float* __restrict__ bhh,
    const int j, const int g, int* __restrict__ flags)
{
  constexpr int KST  = KXS + 2;
  constexpr int D    = (KXS == 1) ? 28 : 64;
  constexpr int KX   = KXS * 32;
  constexpr int RATE = 1 << LAYER;
  constexpr int SRCR = (LAYER > 0) ? (RATE >> 1) : 1;

  const int i    = threadIdx.x;
  const int lane = i & 63;
  const int wid  = i >> 6;
  const int n15  = lane & 15;
  const int kq   = lane >> 4;
  const int base = g * 16;
  const int wm   = i >> 4;
  const int wu   = (i & 15) * 4;
  const uint km  = (kq == 3) ? 0u : ~0u;

  short8v wfrag[4][KST];
  float bias[4];
  #pragma unroll
  for (int gg = 0; gg < 4; ++gg) {
    const int R = gg*64 + wid*16 + n15;
    bias[gg] = bih[R] + bhh[R];
    #pragma unroll
    for (int kk = 0; kk < KST; ++kk) {
      #pragma unroll
      for (int jj = 0; jj < 8; ++jj) {
        const int k = kk*32 + kq*8 + jj;
        float v;
        if (k < KX) v = (k < D) ? Wih[R*D + k] : 0.f;
        else        v = Whh[R*64 + (k - KX)];
        wfrag[gg][kk][jj] = (short)f2bfu(v);
      }
    }
  }
  f32x4 biasv[4];
  #pragma unroll
  for (int gg = 0; gg < 4; ++gg)
    biasv[gg] = (f32x4){bias[gg], bias[gg], bias[gg], bias[gg]};
  const f32x4 zv = (f32x4){0.f, 0.f, 0.f, 0.f};

  for (int e = i; e < 1152; e += 256) hb[e] = 0;
  __syncthreads();

  const int nsteps = (T_WIN - 1 - j)/RATE + 1;
  const int u = wid*16 + n15;
  float cc[4] = {0.f, 0.f, 0.f, 0.f};

  int* myflag = &flags[(LAYER*8 + j)*NGRP + g];
  int* fp = nullptr;
  int seen0 = 0;
  int prodmax = 0x7fffffff;
  if constexpr (LAYER > 0) {
    const int pp0 = j % SRCR;
    fp = &flags[((LAYER-1)*8 + pp0)*NGRP + g];
    prodmax = (T_WIN - 1 - pp0)/SRCR + 1;
  }

  auto wait_for = [&](int t) __attribute__((always_inline)) {
    if constexpr (LAYER > 0) {
      const int tc = (t < T_WIN) ? t : (T_WIN - 1);
      int need = tc/SRCR + 1;
      need = (need < prodmax) ? need : prodmax;
      if (seen0 >= need) return;
      while (__hip_atomic_load(fp, __ATOMIC_RELAXED, __HIP_MEMORY_SCOPE_AGENT) < need)
        __builtin_amdgcn_s_sleep(8);
      seen0 = __hip_atomic_load(fp, __ATOMIC_ACQUIRE, __HIP_MEMORY_SCOPE_AGENT);
    }
  };

  auto loadx = [&](int t, short8v* xf) __attribute__((always_inline)) {
    const int tc = (t < T_WIN) ? t : (T_WIN - 1);
    const ushort* p = xin + ((size_t)tc*512 + base + n15)*(size_t)D + kq*8;
    if constexpr (D == 64) {
      xf[0] = *reinterpret_cast<const short8v*>(p);
      xf[1] = *reinterpret_cast<const short8v*>(p + 32);
    } else {
      ushort4 a = *reinterpret_cast<const ushort4*>(p);
      ushort4 b = *reinterpret_cast<const ushort4*>(p + 4);
      short8v r;
      r[0]=(short)a.x; r[1]=(short)a.y; r[2]=(short)a.z; r[3]=(short)a.w;
      r[4]=(short)(ushort)(b.x & km); r[5]=(short)(ushort)(b.y & km);
      r[6]=(short)(ushort)(b.z & km); r[7]=(short)(ushort)(b.w & km);
      xf[0] = r;
    }
  };

  auto xmm = [&](const short8v* xf, f32x4* xa) __attribute__((always_inline)) {
    #pragma unroll
    for (int gg = 0; gg < 4; ++gg) {
      f32x4 t = __builtin_amdgcn_mfma_f32_16x16x32_bf16(xf[0], wfrag[gg][0], biasv[gg], 0, 0, 0);
      if constexpr (KXS == 2)
        t = __builtin_amdgcn_mfma_f32_16x16x32_bf16(xf[1], wfrag[gg][1], t, 0, 0, 0);
      xa[gg] = t;
    }
  };

  auto stepc = [&](int S, const f32x4* xaC, f32x4* xaN, short8v* xfN, int tN,
                   uint2* hv, bool doNext) __attribute__((always_inline)) {
    const int p_ = S & 1;
    const ushort* hbp = hb + p_*1152;
    short8v hf0 = *reinterpret_cast<const short8v*>(hbp + n15*72 + kq*8);
    short8v hf1 = *reinterpret_cast<const short8v*>(hbp + n15*72 + 32 + kq*8);
    *hv = *reinterpret_cast<const uint2*>(hbp + wm*72 + wu);
    f32x4 A0 = __builtin_amdgcn_mfma_f32_16x16x32_bf16(hf0, wfrag[0][KXS], xaC[0], 0, 0, 0);
    f32x4 A1 = __builtin_amdgcn_mfma_f32_16x16x32_bf16(hf0, wfrag[1][KXS], xaC[1], 0, 0, 0);
    f32x4 A2 = __builtin_amdgcn_mfma_f32_16x16x32_bf16(hf0, wfrag[2][KXS], xaC[2], 0, 0, 0);
    f32x4 A3 = __builtin_amdgcn_mfma_f32_16x16x32_bf16(hf0, wfrag[3][KXS], xaC[3], 0, 0, 0);
    f32x4 B0 = __builtin_amdgcn_mfma_f32_16x16x32_bf16(hf1, wfrag[0][KXS+1], zv, 0, 0, 0);
    f32x4 B1 = __builtin_amdgcn_mfma_f32_16x16x32_bf16(hf1, wfrag[1][KXS+1], zv, 0, 0, 0);
    f32x4 B2 = __builtin_amdgcn_mfma_f32_16x16x32_bf16(hf1, wfrag[2][KXS+1], zv, 0, 0, 0);
    f32x4 B3 = __builtin_amdgcn_mfma_f32_16x16x32_bf16(hf1, wfrag[3][KXS+1], zv, 0, 0, 0);
    if (doNext) {
      xmm(xfN, xaN);
      loadx(tN, xfN);
    }
    ushort* hbn = hb + (p_^1)*1152;
    #pragma unroll
    for (int r = 0; r < 4; ++r) {
      const float zi = A0[r] + B0[r];
      const float zf = A1[r] + B1[r];
      const float zg = A2[r] + B2[r];
      const float zo = A3[r] + B3[r];
      cc[r] = sigmf(zf)*cc[r] + sigmf(zi)*tanhf_fast(zg);
      const float h_ = sigmf(zo)*tanhf_fast(cc[r]);
      hbn[(kq*4 + r)*72 + u] = f2bfu(h_);
    }
    __builtin_amdgcn_sched_barrier(0);
    __builtin_amdgcn_s_waitcnt(WAIT_LGKM0);
    __builtin_amdgcn_sched_barrier(0);
    __builtin_amdgcn_s_barrier();
  };

  auto sth = [&](int t, uint2 hv) __attribute__((always_inline)) {
    *reinterpret_cast<uint2*>(&hout[((size_t)t*512 + base + wm)*64 + wu]) = hv;
  };

  short8v xf0[KXS], xf1[KXS], xf2[KXS], xf3[KXS];
  f32x4 xaP[4], xaQ[4];
  uint2 hh0, hh1, hh2, hh3;

  wait_for(j + 8*RATE);
  loadx(j, xf0);
  xmm(xf0, xaP);
  loadx(j + 4*RATE, xf0);
  loadx(j +   RATE, xf1);
  loadx(j + 2*RATE, xf2);
  loadx(j + 3*RATE, xf3);

  stepc(0, xaP, xaQ, xf1, j + 5*RATE, &hh0, true);
  stepc(1, xaQ, xaP, xf2, j + 6*RATE, &hh1, true);
  stepc(2, xaP, xaQ, xf3, j + 7*RATE, &hh2, true);
  stepc(3, xaQ, xaP, xf0, j + 8*RATE, &hh3, true);
  sth(j,          hh1);
  sth(j +   RATE, hh2);
  sth(j + 2*RATE, hh3);

  int B = 4;
  for (; B + 4 <= nsteps; B += 4) {
    wait_for(j + (B + 8)*RATE);
    stepc(B+0, xaP, xaQ, xf1, j + (B+5)*RATE, &hh0, true);
    stepc(B+1, xaQ, xaP, xf2, j + (B+6)*RATE, &hh1, true);
    stepc(B+2, xaP, xaQ, xf3, j + (B+7)*RATE, &hh2, true);
    stepc(B+3, xaQ, xaP, xf0, j + (B+8)*RATE, &hh3, true);
    sth(j + (B-1)*RATE, hh0);
    sth(j + (B  )*RATE, hh1);
    sth(j + (B+1)*RATE, hh2);
    sth(j + (B+2)*RATE, hh3);
    if constexpr (LAYER < 3) {
      if ((B & 7) == 4) {
        __builtin_amdgcn_s_waitcnt(WAIT_VM0);
        __builtin_amdgcn_s_barrier();
        if (i == 0)
          __hip_atomic_store(myflag, B+3, __ATOMIC_RELEASE, __HIP_MEMORY_SCOPE_AGENT);
      }
    }
  }
  for (; B < nsteps; ++B) {
    uint2 hvT;
    if (B & 1) stepc(B, xaQ, nullptr, nullptr, 0, &hvT, false);
    else       stepc(B, xaP, nullptr, nullptr, 0, &hvT, false);
    sth(j + (B-1)*RATE, hvT);
  }

  {
    const int pF = nsteps & 1;
    const int tF = j + (nsteps - 1)*RATE;
    uint2 hv = *reinterpret_cast<const uint2*>(hb + pF*1152 + wm*72 + wu);
    sth(tF, hv);
  }
  if constexpr (LAYER < 3) {
    __builtin_amdgcn_s_waitcnt(WAIT_VM0);
    __builtin_amdgcn_s_barrier();
    if (i == 0)
      __hip_atomic_store(myflag, nsteps, __ATOMIC_RELEASE, __HIP_MEMORY_SCOPE_AGENT);
  }
}

__global__ __launch_bounds__(256, 2)
void lstm_fused(const ushort* __restrict__ xhat,
                ushort* __restrict__ h1, ushort* __restrict__ h2, ushort* __restrict__ h4,
                const float* __restrict__ Wih0, const float* __restrict__ Wih_rest,
                const float* __restrict__ Whh_all,
                const float* __restrict__ bih_all, const float* __restrict__ bhh_all,
                int* __restrict__ flags)
{
  __shared__ __align__(16) ushort smem[SMEM_USHORTS];
  const int bid = blockIdx.x;
  ushort* h3 = h1;   // alias safe (pipeline ordering, see r5 analysis)
  if (bid < 32) {
    lstm_scan<1,0>(smem, xhat, h1, Wih0, Whh_all, bih_all, bhh_all,
                   0, bid, flags);
  } else if (bid < 96) {
    lstm_scan<2,1>(smem, h1, h2, Wih_rest, Whh_all + 256*64, bih_all + 256, bhh_all + 256,
                   (bid-32) >> 5, (bid-32) & 31, flags);
  } else if (bid < 224) {
    lstm_scan<2,2>(smem, h2, h3, Wih_rest + 256*64, Whh_all + 2*256*64, bih_all + 2*256, bhh_all + 2*256,
                   (bid-96) >> 5, (bid-96) & 31, flags);
  } else {
    lstm_scan<2,3>(smem, h3, h4, Wih_rest + 2*256*64, Whh_all + 3*256*64, bih_all + 3*256, bhh_all + 3*256,
                   (bid-224) >> 5, (bid-224) & 31, flags);
  }
}

// ---------------- adapter: out1 = (h4+h2) @ adW.T + adb ----------------
__global__ __launch_bounds__(256) void adapter_kernel(const ushort* __restrict__ h4, const ushort* __restrict__ h2,
      const float* __restrict__ adW, const float* __restrict__ adb, float* __restrict__ out) {
  __shared__ __align__(16) float xrow[64*64];
  const int i = threadIdx.x;
  const int total = T_WIN*512;
  const int base = blockIdx.x * 64;
  for (int e = i; e < 512; e += 256) {
    const int r  = e >> 3;
    const int c8 = (e & 7) * 8;
    size_t gi = (size_t)(base + r)*64 + c8;
    if (base + r < total) {
      uint4 a = *reinterpret_cast<const uint4*>(h4 + gi);
      uint4 b = *reinterpret_cast<const uint4*>(h2 + gi);
      const uint* au = &a.x; const uint* bu = &b.x;
      #pragma unroll
      for (int q = 0; q < 4; ++q) {
        uint av = au[q], bv = bu[q];
        xrow[r*64 + c8 + 2*q]     = bfu2f((ushort)(av & 0xFFFF)) + bfu2f((ushort)(bv & 0xFFFF));
        xrow[r*64 + c8 + 2*q + 1] = bfu2f((ushort)(av >> 16))    + bfu2f((ushort)(bv >> 16));
      }
    } else {
      #pragma unroll
      for (int q = 0; q < 8; ++q) xrow[r*64 + c8 + q] = 0.f;
    }
  }
  const int o  = i & 31;
  const int rg = i >> 5;
  float w[64]; float bo = 0.f;
  if (o < 28) {
    #pragma unroll
    for (int uu=0;uu<64;++uu) w[uu] = adW[o*64+uu];
    bo = adb[o];
  }
  __syncthreads();
  if (o < 28) {
    #pragma unroll
    for (int rr=0; rr<8; ++rr) {
      int r = rg*8 + rr;
      if (base + r >= total) break;
      const float4* xp = (const float4*)(&xrow[r*64]);
      float a0 = bo, a1 = 0.f, a2 = 0.f, a3 = 0.f;
      #pragma unroll
      for (int q=0;q<16;++q) {
        float4 xv = xp[q];
        a0 += w[4*q+0]*xv.x; a1 += w[4*q+1]*xv.y;
        a2 += w[4*q+2]*xv.z; a3 += w[4*q+3]*xv.w;
      }
      out[(size_t)(base+r)*28 + o] = (a0+a1)+(a2+a3);
    }
  }
}

extern "C" void kernel_launch(void* const* d_in, const int* in_sizes, int n_in,
                              void* d_out, int out_size, void* d_ws, size_t ws_size,
                              hipStream_t stream) {
  const float* y         = (const float*)d_in[0];
  const int*   idxs      = (const int*)d_in[1];
  const float* noise     = (const float*)d_in[2];
  const float* lev_sms   = (const float*)d_in[3];
  const float* seas_sms  = (const float*)d_in[4];
  const float* init_seas = (const float*)d_in[5];
  const float* Wih0      = (const float*)d_in[6];
  const float* Wih_rest  = (const float*)d_in[7];
  const float* Whh_all   = (const float*)d_in[8];
  const float* bih_all   = (const float*)d_in[9];
  const float* bhh_all   = (const float*)d_in[10];
  const float* adW       = (const float*)d_in[11];
  const float* adb       = (const float*)d_in[12];

  const size_t NWIN28 = (size_t)T_WIN*512*28;
  const size_t NWIN64 = (size_t)T_WIN*512*64;
  const size_t NYT    = (size_t)NSER*NTIME;
  float* out_wy   = (float*)d_out;
  float* out_yhat = out_wy + NWIN28;
  float* out_lev  = out_yhat + NWIN28;

  int*   flags = (int*)d_ws;                       // 4 KiB reserved
  float* yT    = (float*)((char*)d_ws + 4096);
  float* levT  = yT    + NYT;
  float* seasT = levT  + NYT;
  float* lnorm = seasT + NYT;
  float* llev  = lnorm + NYT;
  ushort* xhat = (ushort*)(llev + NYT);
  ushort* h1   = (ushort*)((char*)xhat + NWIN28*2);
  ushort* h2   = (ushort*)((char*)h1 + NWIN64*2);
  ushort* h4   = (ushort*)((char*)h2 + NWIN64*2);

  size_t need = 4096 + (size_t)5*NYT*4 + NWIN28*2 + 3*NWIN64*2;
  if (ws_size < need) {
    fprintf(stderr, "kernel_launch: ws_size %zu < needed %zu\n", ws_size, need);
    return;
  }

  hipMemsetAsync(flags, 0, FLAGS_INTS*sizeof(int), stream);
  transpose_y<<<256,256,0,stream>>>(y, yT);
  es_kernel_t<<<2,256,0,stream>>>(yT, idxs, lev_sms, seas_sms, init_seas, levT, seasT);
  trlog_kernel<<<256,256,0,stream>>>(y, levT, seasT, out_lev, lnorm, llev);
  window_kernel<<<NWIN28/256,256,0,stream>>>(lnorm, llev, noise, out_wy, xhat);

  lstm_fused<<<480,256,0,stream>>>(xhat, h1, h2, h4, Wih0, Wih_rest, Whh_all,
                                   bih_all, bhh_all, flags);

  adapter_kernel<<<(T_WIN*512)/64,256,0,stream>>>(h4, h2, adW, adb, out_yhat);
}

// Round 16
// 3175.735 us; speedup vs baseline: 1.3768x; 1.0376x over previous
//
#include <hip/hip_runtime.h>
#include <hip/hip_bf16.h>
#include <cstdio>

typedef __hip_bfloat16 bf16;
typedef __attribute__((ext_vector_type(8))) short short8v;
typedef __attribute__((ext_vector_type(4))) float f32x4;

#define T_WIN 1993      // N_WINDOWS
#define NSER 512
#define NTIME 2048
#define NGRP 32
#define FLAGS_INTS (4*8*NGRP)

#define WAIT_LGKM0 0xC07F   // lgkmcnt(0) only
#define WAIT_VM0   0x0F70   // vmcnt(0) only

#define SMEM_USHORTS 2304   // hbuf: 2 × 16×72 ushorts (4608 B)

__device__ __forceinline__ float sigmf(float x) { return __fdividef(1.f, 1.f + __expf(-x)); }
__device__ __forceinline__ float tanhf_fast(float x) { return 1.f - __fdividef(2.f, __expf(2.f*x) + 1.f); }
__device__ __forceinline__ ushort f2bfu(float f) {
  __hip_bfloat16 h = __float2bfloat16(f);
  return *reinterpret_cast<ushort*>(&h);
}
__device__ __forceinline__ float bfu2f(ushort u) {
  uint x = ((uint)u) << 16;
  return __uint_as_float(x);
}

// ---------------- y[s][t] -> yT[t][s] (LDS-tiled, conflict-free) -----------
__global__ __launch_bounds__(256) void transpose_y(const float* __restrict__ y,
                                                   float* __restrict__ yT) {
  __shared__ float tile[64][65];
  const int i  = threadIdx.x;
  const int c  = i & 63;
  const int r4 = i >> 6;
  const int t0 = (blockIdx.x & 31) * 64;
  const int s0 = (blockIdx.x >> 5) * 64;
  #pragma unroll
  for (int q = 0; q < 16; ++q) {
    const int sl = q*4 + r4;
    tile[c][sl] = y[(size_t)(s0 + sl)*NTIME + t0 + c];
  }
  __syncthreads();
  #pragma unroll
  for (int q = 0; q < 16; ++q) {
    const int tl = q*4 + r4;
    yT[(size_t)(t0 + tl)*NSER + s0 + c] = tile[tl][c];
  }
}

// ---------------- ES scan (transposed layouts; all accesses coalesced) -----
__global__ void es_kernel_t(const float* __restrict__ yT, const int* __restrict__ idxs,
                            const float* __restrict__ lev_sms, const float* __restrict__ seas_sms,
                            const float* __restrict__ init_seas,
                            float* __restrict__ levT, float* __restrict__ seasT) {
  int s = blockIdx.x*blockDim.x + threadIdx.x;
  if (s >= NSER) return;
  int id = idxs[s];
  float ls = sigmf(lev_sms[id]);
  float ss = sigmf(seas_sms[id]);
  float buf[8];
  #pragma unroll
  for (int k=0;k<7;++k) buf[k] = __expf(init_seas[id*7+k]);
  buf[7] = buf[0];
  float lev = __fdividef(yT[s], buf[0]);
  levT[s] = lev;
  #pragma unroll
  for (int t=0;t<8;++t) seasT[t*NSER + s] = buf[t];
  #pragma unroll 8
  for (int t=1;t<NTIME;++t) {
    float yt = yT[t*NSER + s];
    float st = buf[1];
    lev = ls*__fdividef(yt,st) + (1.f-ls)*lev;
    float ns = ss*__fdividef(yt,lev) + (1.f-ss)*st;
    #pragma unroll
    for (int k=0;k<7;++k) buf[k] = buf[k+1];
    buf[7] = ns;
    levT[t*NSER + s] = lev;
    if (t+7 < NTIME) seasT[(t+7)*NSER + s] = ns;
  }
}

// ------- transpose back + fused logs: out_lev/lnorm/llev in [s][t] ---------
__global__ __launch_bounds__(256) void trlog_kernel(const float* __restrict__ y,
        const float* __restrict__ levT, const float* __restrict__ seasT,
        float* __restrict__ out_lev, float* __restrict__ lnorm, float* __restrict__ llev) {
  __shared__ float tl[64][65];
  __shared__ float ts[64][65];
  const int i  = threadIdx.x;
  const int c  = i & 63;
  const int r4 = i >> 6;
  const int t0 = (blockIdx.x & 31) * 64;
  const int s0 = (blockIdx.x >> 5) * 64;
  #pragma unroll
  for (int q = 0; q < 16; ++q) {
    const int tl_ = q*4 + r4;
    const size_t src = (size_t)(t0 + tl_)*NSER + s0 + c;
    tl[tl_][c] = levT[src];
    ts[tl_][c] = seasT[src];
  }
  __syncthreads();
  #pragma unroll
  for (int q = 0; q < 16; ++q) {
    const int sl = q*4 + r4;
    const size_t o = (size_t)(s0 + sl)*NTIME + t0 + c;
    const float lv = tl[c][sl];
    const float sv = ts[c][sl];
    out_lev[o] = lv;
    llev[o]    = __logf(lv);
    lnorm[o]   = __logf(__fdividef(y[o], sv));
  }
}

// ------- windows: grid-stride, 4 elements/thread (launch-rate fix) ---------
// old grid was 111,608 tiny blocks -> dispatch-rate bound (~700 µs).
__global__ __launch_bounds__(256) void window_kernel(const float* __restrict__ lnorm,
                              const float* __restrict__ llev,
                              const float* __restrict__ noise,
                              float* __restrict__ wy, ushort* __restrict__ xhat) {
  const int NQ = (T_WIN*512*28)/4;              // 7,142,912 quads
  const int nth = gridDim.x * 256;
  for (int e = blockIdx.x*256 + threadIdx.x; e < NQ; e += nth) {
    const int k4 = (e % 7) * 4;                 // idx4 = (e/7)*28 + (e%7)*4
    const int rs = e / 7;
    const int s  = rs & 511;
    const int w  = rs >> 9;
    const float lv = llev[s*NTIME + 28 + w];
    const float* Ln = lnorm + (size_t)s*NTIME + w + k4;
    const float4 nz = *reinterpret_cast<const float4*>(noise + (size_t)e*4);
    float4 wv;
    wv.x = Ln[28] - lv; wv.y = Ln[29] - lv; wv.z = Ln[30] - lv; wv.w = Ln[31] - lv;
    *reinterpret_cast<float4*>(wy + (size_t)e*4) = wv;
    ushort4 xv;
    xv.x = f2bfu(Ln[0] - lv + 0.001f*nz.x);
    xv.y = f2bfu(Ln[1] - lv + 0.001f*nz.y);
    xv.z = f2bfu(Ln[2] - lv + 0.001f*nz.z);
    xv.w = f2bfu(Ln[3] - lv + 0.001f*nz.w);
    *reinterpret_cast<ushort4*>(xhat + (size_t)e*4) = xv;
  }
}

// ---------------- fused 4-layer pipelined LSTM scan (production, r14) ------
template<int KXS, int LAYER>
__device__ __forceinline__ void lstm_scan(
    ushort* __restrict__ hb,
    const ushort* __restrict__ xin, ushort* __restrict__ hout,
    const float* __restrict__ Wih, const float* __restrict__ Whh,
    const float* __restrict__ bih, const float* __restrict__ bhh,
    const int j, const int g, int* __restrict__ flags)
{
  constexpr int KST  = KXS + 2;
  constexpr int D    = (KXS == 1) ? 28 : 64;
  constexpr int KX   = KXS * 32;
  constexpr int RATE = 1 << LAYER;
  constexpr int SRCR = (LAYER > 0) ? (RATE >> 1) : 1;

  const int i    = threadIdx.x;
  const int lane = i & 63;
  const int wid  = i >> 6;
  const int n15  = lane & 15;
  const int kq   = lane >> 4;
  const int base = g * 16;
  const int wm   = i >> 4;
  const int wu   = (i & 15) * 4;
  const uint km  = (kq == 3) ? 0u : ~0u;

  short8v wfrag[4][KST];
  float bias[4];
  #pragma unroll
  for (int gg = 0; gg < 4; ++gg) {
    const int R = gg*64 + wid*16 + n15;
    bias[gg] = bih[R] + bhh[R];
    #pragma unroll
    for (int kk = 0; kk < KST; ++kk) {
      #pragma unroll
      for (int jj = 0; jj < 8; ++jj) {
        const int k = kk*32 + kq*8 + jj;
        float v;
        if (k < KX) v = (k < D) ? Wih[R*D + k] : 0.f;
        else        v = Whh[R*64 + (k - KX)];
        wfrag[gg][kk][jj] = (short)f2bfu(v);
      }
    }
  }
  f32x4 biasv[4];
  #pragma unroll
  for (int gg = 0; gg < 4; ++gg)
    biasv[gg] = (f32x4){bias[gg], bias[gg], bias[gg], bias[gg]};
  const f32x4 zv = (f32x4){0.f, 0.f, 0.f, 0.f};

  for (int e = i; e < 1152; e += 256) hb[e] = 0;
  __syncthreads();

  const int nsteps = (T_WIN - 1 - j)/RATE + 1;
  const int u = wid*16 + n15;
  float cc[4] = {0.f, 0.f, 0.f, 0.f};

  int* myflag = &flags[(LAYER*8 + j)*NGRP + g];
  int* fp = nullptr;
  int seen0 = 0;
  int prodmax = 0x7fffffff;
  if constexpr (LAYER > 0) {
    const int pp0 = j % SRCR;
    fp = &flags[((LAYER-1)*8 + pp0)*NGRP + g];
    prodmax = (T_WIN - 1 - pp0)/SRCR + 1;
  }

  auto wait_for = [&](int t) __attribute__((always_inline)) {
    if constexpr (LAYER > 0) {
      const int tc = (t < T_WIN) ? t : (T_WIN - 1);
      int need = tc/SRCR + 1;
      need = (need < prodmax) ? need : prodmax;
      if (seen0 >= need) return;
      while (__hip_atomic_load(fp, __ATOMIC_RELAXED, __HIP_MEMORY_SCOPE_AGENT) < need)
        __builtin_amdgcn_s_sleep(8);
      seen0 = __hip_atomic_load(fp, __ATOMIC_ACQUIRE, __HIP_MEMORY_SCOPE_AGENT);
    }
  };

  auto loadx = [&](int t, short8v* xf) __attribute__((always_inline)) {
    const int tc = (t < T_WIN) ? t : (T_WIN - 1);
    const ushort* p = xin + ((size_t)tc*512 + base + n15)*(size_t)D + kq*8;
    if constexpr (D == 64) {
      xf[0] = *reinterpret_cast<const short8v*>(p);
      xf[1] = *reinterpret_cast<const short8v*>(p + 32);
    } else {
      ushort4 a = *reinterpret_cast<const ushort4*>(p);
      ushort4 b = *reinterpret_cast<const ushort4*>(p + 4);
      short8v r;
      r[0]=(short)a.x; r[1]=(short)a.y; r[2]=(short)a.z; r[3]=(short)a.w;
      r[4]=(short)(ushort)(b.x & km); r[5]=(short)(ushort)(b.y & km);
      r[6]=(short)(ushort)(b.z & km); r[7]=(short)(ushort)(b.w & km);
      xf[0] = r;
    }
  };

  auto xmm = [&](const short8v* xf, f32x4* xa) __attribute__((always_inline)) {
    #pragma unroll
    for (int gg = 0; gg < 4; ++gg) {
      f32x4 t = __builtin_amdgcn_mfma_f32_16x16x32_bf16(xf[0], wfrag[gg][0], biasv[gg], 0, 0, 0);
      if constexpr (KXS == 2)
        t = __builtin_amdgcn_mfma_f32_16x16x32_bf16(xf[1], wfrag[gg][1], t, 0, 0, 0);
      xa[gg] = t;
    }
  };

  auto stepc = [&](int S, const f32x4* xaC, f32x4* xaN, short8v* xfN, int tN,
                   uint2* hv, bool doNext) __attribute__((always_inline)) {
    const int p_ = S & 1;
    const ushort* hbp = hb + p_*1152;
    short8v hf0 = *reinterpret_cast<const short8v*>(hbp + n15*72 + kq*8);
    short8v hf1 = *reinterpret_cast<const short8v*>(hbp + n15*72 + 32 + kq*8);
    *hv = *reinterpret_cast<const uint2*>(hbp + wm*72 + wu);
    f32x4 A0 = __builtin_amdgcn_mfma_f32_16x16x32_bf16(hf0, wfrag[0][KXS], xaC[0], 0, 0, 0);
    f32x4 A1 = __builtin_amdgcn_mfma_f32_16x16x32_bf16(hf0, wfrag[1][KXS], xaC[1], 0, 0, 0);
    f32x4 A2 = __builtin_amdgcn_mfma_f32_16x16x32_bf16(hf0, wfrag[2][KXS], xaC[2], 0, 0, 0);
    f32x4 A3 = __builtin_amdgcn_mfma_f32_16x16x32_bf16(hf0, wfrag[3][KXS], xaC[3], 0, 0, 0);
    f32x4 B0 = __builtin_amdgcn_mfma_f32_16x16x32_bf16(hf1, wfrag[0][KXS+1], zv, 0, 0, 0);
    f32x4 B1 = __builtin_amdgcn_mfma_f32_16x16x32_bf16(hf1, wfrag[1][KXS+1], zv, 0, 0, 0);
    f32x4 B2 = __builtin_amdgcn_mfma_f32_16x16x32_bf16(hf1, wfrag[2][KXS+1], zv, 0, 0, 0);
    f32x4 B3 = __builtin_amdgcn_mfma_f32_16x16x32_bf16(hf1, wfrag[3][KXS+1], zv, 0, 0, 0);
    if (doNext) {
      xmm(xfN, xaN);
      loadx(tN, xfN);
    }
    ushort* hbn = hb + (p_^1)*1152;
    #pragma unroll
    for (int r = 0; r < 4; ++r) {
      const float zi = A0[r] + B0[r];
      const float zf = A1[r] + B1[r];
      const float zg = A2[r] + B2[r];
      const float zo = A3[r] + B3[r];
      cc[r] = sigmf(zf)*cc[r] + sigmf(zi)*tanhf_fast(zg);
      const float h_ = sigmf(zo)*tanhf_fast(cc[r]);
      hbn[(kq*4 + r)*72 + u] = f2bfu(h_);
    }
    __builtin_amdgcn_sched_barrier(0);
    __builtin_amdgcn_s_waitcnt(WAIT_LGKM0);
    __builtin_amdgcn_sched_barrier(0);
    __builtin_amdgcn_s_barrier();
  };

  auto sth = [&](int t, uint2 hv) __attribute__((always_inline)) {
    *reinterpret_cast<uint2*>(&hout[((size_t)t*512 + base + wm)*64 + wu]) = hv;
  };

  short8v xf0[KXS], xf1[KXS], xf2[KXS], xf3[KXS];
  f32x4 xaP[4], xaQ[4];
  uint2 hh0, hh1, hh2, hh3;

  wait_for(j + 8*RATE);
  loadx(j, xf0);
  xmm(xf0, xaP);
  loadx(j + 4*RATE, xf0);
  loadx(j +   RATE, xf1);
  loadx(j + 2*RATE, xf2);
  loadx(j + 3*RATE, xf3);

  stepc(0, xaP, xaQ, xf1, j + 5*RATE, &hh0, true);
  stepc(1, xaQ, xaP, xf2, j + 6*RATE, &hh1, true);
  stepc(2, xaP, xaQ, xf3, j + 7*RATE, &hh2, true);
  stepc(3, xaQ, xaP, xf0, j + 8*RATE, &hh3, true);
  sth(j,          hh1);
  sth(j +   RATE, hh2);
  sth(j + 2*RATE, hh3);

  int B = 4;
  for (; B + 4 <= nsteps; B += 4) {
    wait_for(j + (B + 8)*RATE);
    stepc(B+0, xaP, xaQ, xf1, j + (B+5)*RATE, &hh0, true);
    stepc(B+1, xaQ, xaP, xf2, j + (B+6)*RATE, &hh1, true);
    stepc(B+2, xaP, xaQ, xf3, j + (B+7)*RATE, &hh2, true);
    stepc(B+3, xaQ, xaP, xf0, j + (B+8)*RATE, &hh3, true);
    sth(j + (B-1)*RATE, hh0);
    sth(j + (B  )*RATE, hh1);
    sth(j + (B+1)*RATE, hh2);
    sth(j + (B+2)*RATE, hh3);
    if constexpr (LAYER < 3) {
      if ((B & 7) == 4) {
        __builtin_amdgcn_s_waitcnt(WAIT_VM0);
        __builtin_amdgcn_s_barrier();
        if (i == 0)
          __hip_atomic_store(myflag, B+3, __ATOMIC_RELEASE, __HIP_MEMORY_SCOPE_AGENT);
      }
    }
  }
  for (; B < nsteps; ++B) {
    uint2 hvT;
    if (B & 1) stepc(B, xaQ, nullptr, nullptr, 0, &hvT, false);
    else       stepc(B, xaP, nullptr, nullptr, 0, &hvT, false);
    sth(j + (B-1)*RATE, hvT);
  }

  {
    const int pF = nsteps & 1;
    const int tF = j + (nsteps - 1)*RATE;
    uint2 hv = *reinterpret_cast<const uint2*>(hb + pF*1152 + wm*72 + wu);
    sth(tF, hv);
  }
  if constexpr (LAYER < 3) {
    __builtin_amdgcn_s_waitcnt(WAIT_VM0);
    __builtin_amdgcn_s_barrier();
    if (i == 0)
      __hip_atomic_store(myflag, nsteps, __ATOMIC_RELEASE, __HIP_MEMORY_SCOPE_AGENT);
  }
}

__global__ __launch_bounds__(256, 2)
void lstm_fused(const ushort* __restrict__ xhat,
                ushort* __restrict__ h1, ushort* __restrict__ h2, ushort* __restrict__ h4,
                const float* __restrict__ Wih0, const float* __restrict__ Wih_rest,
                const float* __restrict__ Whh_all,
                const float* __restrict__ bih_all, const float* __restrict__ bhh_all,
                int* __restrict__ flags)
{
  __shared__ __align__(16) ushort smem[SMEM_USHORTS];
  const int bid = blockIdx.x;
  ushort* h3 = h1;   // alias safe (pipeline ordering, see r5 analysis)
  if (bid < 32) {
    lstm_scan<1,0>(smem, xhat, h1, Wih0, Whh_all, bih_all, bhh_all,
                   0, bid, flags);
  } else if (bid < 96) {
    lstm_scan<2,1>(smem, h1, h2, Wih_rest, Whh_all + 256*64, bih_all + 256, bhh_all + 256,
                   (bid-32) >> 5, (bid-32) & 31, flags);
  } else if (bid < 224) {
    lstm_scan<2,2>(smem, h2, h3, Wih_rest + 256*64, Whh_all + 2*256*64, bih_all + 2*256, bhh_all + 2*256,
                   (bid-96) >> 5, (bid-96) & 31, flags);
  } else {
    lstm_scan<2,3>(smem, h3, h4, Wih_rest + 2*256*64, Whh_all + 3*256*64, bih_all + 3*256, bhh_all + 3*256,
                   (bid-224) >> 5, (bid-224) & 31, flags);
  }
}

// ------- adapter: grid-stride over 64-row tiles (launch-rate fix) ----------
__global__ __launch_bounds__(256) void adapter_kernel(const ushort* __restrict__ h4, const ushort* __restrict__ h2,
      const float* __restrict__ adW, const float* __restrict__ adb, float* __restrict__ out) {
  __shared__ __align__(16) float xrow[64*64];
  const int i = threadIdx.x;
  const int ntiles = (T_WIN*512)/64;   // 15,944 exactly
  const int o  = i & 31;
  const int rg = i >> 5;
  float w[64]; float bo = 0.f;
  if (o < 28) {
    #pragma unroll
    for (int uu=0;uu<64;++uu) w[uu] = adW[o*64+uu];
    bo = adb[o];
  }
  for (int tile = blockIdx.x; tile < ntiles; tile += gridDim.x) {
    const int base = tile * 64;
    __syncthreads();   // xrow safe to overwrite (prev iter's readers done)
    for (int e = i; e < 512; e += 256) {
      const int r  = e >> 3;
      const int c8 = (e & 7) * 8;
      size_t gi = (size_t)(base + r)*64 + c8;
      uint4 a = *reinterpret_cast<const uint4*>(h4 + gi);
      uint4 b = *reinterpret_cast<const uint4*>(h2 + gi);
      const uint* au = &a.x; const uint* bu = &b.x;
      #pragma unroll
      for (int q = 0; q < 4; ++q) {
        uint av = au[q], bv = bu[q];
        xrow[r*64 + c8 + 2*q]     = bfu2f((ushort)(av & 0xFFFF)) + bfu2f((ushort)(bv & 0xFFFF));
        xrow[r*64 + c8 + 2*q + 1] = bfu2f((ushort)(av >> 16))    + bfu2f((ushort)(bv >> 16));
      }
    }
    __syncthreads();
    if (o < 28) {
      #pragma unroll
      for (int rr=0; rr<8; ++rr) {
        int r = rg*8 + rr;
        const float4* xp = (const float4*)(&xrow[r*64]);
        float a0 = bo, a1 = 0.f, a2 = 0.f, a3 = 0.f;
        #pragma unroll
        for (int q=0;q<16;++q) {
          float4 xv = xp[q];
          a0 += w[4*q+0]*xv.x; a1 += w[4*q+1]*xv.y;
          a2 += w[4*q+2]*xv.z; a3 += w[4*q+3]*xv.w;
        }
        out[(size_t)(base+r)*28 + o] = (a0+a1)+(a2+a3);
      }
    }
  }
}

extern "C" void kernel_launch(void* const* d_in, const int* in_sizes, int n_in,
                              void* d_out, int out_size, void* d_ws, size_t ws_size,
                              hipStream_t stream) {
  const float* y         = (const float*)d_in[0];
  const int*   idxs      = (const int*)d_in[1];
  const float* noise     = (const float*)d_in[2];
  const float* lev_sms   = (const float*)d_in[3];
  const float* seas_sms  = (const float*)d_in[4];
  const float* init_seas = (const float*)d_in[5];
  const float* Wih0      = (const float*)d_in[6];
  const float* Wih_rest  = (const float*)d_in[7];
  const float* Whh_all   = (const float*)d_in[8];
  const float* bih_all   = (const float*)d_in[9];
  const float* bhh_all   = (const float*)d_in[10];
  const float* adW       = (const float*)d_in[11];
  const float* adb       = (const float*)d_in[12];

  const size_t NWIN28 = (size_t)T_WIN*512*28;
  const size_t NWIN64 = (size_t)T_WIN*512*64;
  const size_t NYT    = (size_t)NSER*NTIME;
  float* out_wy   = (float*)d_out;
  float* out_yhat = out_wy + NWIN28;
  float* out_lev  = out_yhat + NWIN28;

  int*   flags = (int*)d_ws;                       // 4 KiB reserved
  float* yT    = (float*)((char*)d_ws + 4096);
  float* levT  = yT    + NYT;
  float* seasT = levT  + NYT;
  float* lnorm = seasT + NYT;
  float* llev  = lnorm + NYT;
  ushort* xhat = (ushort*)(llev + NYT);
  ushort* h1   = (ushort*)((char*)xhat + NWIN28*2);
  ushort* h2   = (ushort*)((char*)h1 + NWIN64*2);
  ushort* h4   = (ushort*)((char*)h2 + NWIN64*2);

  size_t need = 4096 + (size_t)5*NYT*4 + NWIN28*2 + 3*NWIN64*2;
  if (ws_size < need) {
    fprintf(stderr, "kernel_launch: ws_size %zu < needed %zu\n", ws_size, need);
    return;
  }

  hipMemsetAsync(flags, 0, FLAGS_INTS*sizeof(int), stream);
  transpose_y<<<256,256,0,stream>>>(y, yT);
  es_kernel_t<<<2,256,0,stream>>>(yT, idxs, lev_sms, seas_sms, init_seas, levT, seasT);
  trlog_kernel<<<256,256,0,stream>>>(y, levT, seasT, out_lev, lnorm, llev);
  window_kernel<<<2048,256,0,stream>>>(lnorm, llev, noise, out_wy, xhat);

  lstm_fused<<<480,256,0,stream>>>(xhat, h1, h2, h4, Wih0, Wih_rest, Whh_all,
                                   bih_all, bhh_all, flags);

  adapter_kernel<<<2048,256,0,stream>>>(h4, h2, adW, adb, out_yhat);
}